// Round 5
// baseline (195.923 us; speedup 1.0000x reference)
//
#include <hip/hip_runtime.h>

typedef __attribute__((ext_vector_type(8))) short bf16x8;
typedef __attribute__((ext_vector_type(4))) float f32x4;

#define SZQKV 12582912  // B*N*C = one (q|k|v) output block, elements

__device__ __forceinline__ unsigned short f2bf(float f) {
    unsigned int u = __float_as_uint(f);
    unsigned int r = (u + 0x7FFFu + ((u >> 16) & 1u)) >> 16;
    return (unsigned short)r;
}

// pack two f32 -> two bf16 (round-half-up) in one u32 via v_perm
__device__ __forceinline__ unsigned int pack2bf(float lo, float hi) {
    unsigned int ul = __float_as_uint(lo) + 0x8000u;
    unsigned int uh = __float_as_uint(hi) + 0x8000u;
    return __builtin_amdgcn_perm(uh, ul, 0x07060302u);
}

#define GLDS16(g, l) __builtin_amdgcn_global_load_lds( \
    (const __attribute__((address_space(1))) unsigned int*)(g), \
    (__attribute__((address_space(3))) unsigned int*)(l), 16, 0, 0)

// ---------------- cast weights f32 -> bf16 ----------------
__global__ void cast_w(const float* __restrict__ wqkv,
                       const float* __restrict__ wproj,
                       unsigned short* __restrict__ dst) {
    const int T1 = 1769472;        // w_qkv
    const int T2 = T1 + 589824;    // + w_proj
    int stride = gridDim.x * blockDim.x * 4;
    for (int base = (blockIdx.x * blockDim.x + threadIdx.x) * 4; base < T2; base += stride) {
        const float* src; int off;
        if (base < T1) { src = wqkv; off = base; }
        else           { src = wproj; off = base - T1; }
        float4 v = *(const float4*)(src + off);
        ushort4 o;
        o.x = f2bf(v.x); o.y = f2bf(v.y); o.z = f2bf(v.z); o.w = f2bf(v.w);
        *(ushort4*)(dst + base) = o;
    }
}

// shared fragment-read + MFMA macros (256x256 tile, BK=64, 8 waves 2m x 4n)
#define LDA4(base_, xt_) do { \
    _Pragma("unroll") \
    for (int mi = 0; mi < 4; ++mi) \
        av[mi] = *(const bf16x8*)(bufA + (rA + (base_) + mi * 16) * 128 + (xt_)); \
} while (0)

#define LDB4(xt_) do { \
    _Pragma("unroll") \
    for (int ni = 0; ni < 4; ++ni) \
        bv[ni] = *(const bf16x8*)(bufB + (rB + ni * 16) * 128 + (xt_)); \
} while (0)

#define MM(rbase_) do { \
    __builtin_amdgcn_s_setprio(1); \
    _Pragma("unroll") \
    for (int mi = 0; mi < 4; ++mi) \
    _Pragma("unroll") \
    for (int ni = 0; ni < 4; ++ni) \
        acc[(rbase_) + mi][ni] = __builtin_amdgcn_mfma_f32_16x16x32_bf16(av[mi], bv[ni], acc[(rbase_) + mi][ni], 0, 0, 0); \
    __builtin_amdgcn_s_setprio(0); \
} while (0)

// ---------------- GEMM1: qkv = x @ w_qkv^T (x f32, fused cast; transposed epilogue) ----------------
// X: [16384][768] f32. Bw: [2304][768] bf16. Out: q/k/v f32 [dil*4+b][c'][n] blocks in d_out.
// A staged via reg (f32->bf16 v_perm pack, swizzled ds_write); B via global_load_lds.
// vmcnt protocol per tile: issue 8 A-loads, fence, 4 B-GLDS; vmcnt(12) -> prev B landed;
// barrier1; compute; vmcnt(4) -> A landed (B kt+1 in flight); ds_write A; lgkmcnt; barrier2.
__global__ __launch_bounds__(512, 2) void gemm_qkv(const float* __restrict__ X,
                                                   const unsigned short* __restrict__ Bw,
                                                   float* __restrict__ dout) {
    __shared__ unsigned char lds8[131072];
    const int t = threadIdx.x;
    const int lane = t & 63;
    const int w = t >> 6;
    const int wm = w >> 2, wn = w & 3;

    const int cpx = gridDim.x >> 3;
    const int orig = blockIdx.x;
    const int wgid = (orig & 7) * cpx + (orig >> 3);
    const int bx = wgid / 9, by = wgid - bx * 9;
    const int m0 = bx * 256, n0 = by * 256;

    const unsigned char* Xb = (const unsigned char*)X;
    const unsigned char* Bb = (const unsigned char*)Bw;

    // A reg-staging geometry: thread t -> rows (t>>3)+g*64, chunk j=t&7 (8 bf16 = 32B f32)
    const int arow = t >> 3;
    const int aj = t & 7;
    const size_t aSrc = (size_t)(m0 + arow) * 3072 + aj * 32;
    const int aDst = arow * 128 + ((aj ^ (arow & 7)) << 4);

    // B GLDS staging (inverse-swizzled source, linear LDS dst)
    const int jx = ((t & 7) ^ (arow & 7)) << 4;
    const size_t bSrc = (size_t)(n0 + arow) * 1536 + jx;
    const int ldst = t * 16;

    const int rA = wm * 128 + (lane & 15);
    const int rB = wn * 64 + (lane & 15);
    const int xt0 = (((lane >> 4)) ^ (lane & 7)) << 4;
    const int xt1 = ((4 + (lane >> 4)) ^ (lane & 7)) << 4;

    f32x4 acc[8][4] = {};
    f32x4 ar[8];

#define ALOAD(kt) do { \
    const unsigned char* s_ = Xb + aSrc + (size_t)(kt) * 256; \
    _Pragma("unroll") \
    for (int g = 0; g < 4; ++g) { \
        ar[2*g]   = *(const f32x4*)(s_ + (size_t)g * 196608); \
        ar[2*g+1] = *(const f32x4*)(s_ + (size_t)g * 196608 + 16); \
    } \
} while (0)

#define BSTAGE(kt, bsel) do { \
    unsigned char* db_ = lds8 + (bsel) * 65536 + 32768; \
    const size_t ko_ = (size_t)(kt) * 128; \
    GLDS16(Bb + bSrc + ko_,          db_ + ldst); \
    GLDS16(Bb + bSrc + ko_ + 98304,  db_ + ldst + 8192); \
    GLDS16(Bb + bSrc + ko_ + 196608, db_ + ldst + 16384); \
    GLDS16(Bb + bSrc + ko_ + 294912, db_ + ldst + 24576); \
} while (0)

#define AWRITE(bsel) do { \
    unsigned char* da_ = lds8 + (bsel) * 65536; \
    _Pragma("unroll") \
    for (int g = 0; g < 4; ++g) { \
        uint4 pv; \
        pv.x = pack2bf(ar[2*g][0],   ar[2*g][1]); \
        pv.y = pack2bf(ar[2*g][2],   ar[2*g][3]); \
        pv.z = pack2bf(ar[2*g+1][0], ar[2*g+1][1]); \
        pv.w = pack2bf(ar[2*g+1][2], ar[2*g+1][3]); \
        *(uint4*)(da_ + aDst + g * 8192) = pv; \
    } \
} while (0)

    // prologue: stage tile 0
    ALOAD(0);
    asm volatile("" ::: "memory");
    BSTAGE(0, 0);
    asm volatile("s_waitcnt vmcnt(4)" ::: "memory");   // A(0) landed, B(0) in flight
    AWRITE(0);
    asm volatile("s_waitcnt lgkmcnt(0)" ::: "memory");

    for (int kt = 0; kt < 12; ++kt) {
        if (kt < 11) {
            ALOAD(kt + 1);
            asm volatile("" ::: "memory");             // pin A-loads before B-GLDS
            BSTAGE(kt + 1, (kt + 1) & 1);
            asm volatile("s_waitcnt vmcnt(12)" ::: "memory");  // B(kt) landed
        } else {
            asm volatile("s_waitcnt vmcnt(0)" ::: "memory");
        }
        __builtin_amdgcn_s_barrier();                  // publish tile kt
        asm volatile("" ::: "memory");
        const unsigned char* bufA = lds8 + (kt & 1) * 65536;
        const unsigned char* bufB = bufA + 32768;
        bf16x8 av[4], bv[4];
        LDA4(0, xt0); LDB4(xt0); MM(0);
        LDA4(64, xt0); MM(4);
        LDA4(0, xt1); LDB4(xt1); MM(0);
        LDA4(64, xt1); MM(4);
        if (kt < 11) {
            asm volatile("s_waitcnt vmcnt(4)" ::: "memory");   // A(kt+1) regs arrived
            AWRITE((kt + 1) & 1);
        }
        asm volatile("s_waitcnt lgkmcnt(0)" ::: "memory");
        __builtin_amdgcn_s_barrier();                  // release cur buffer
        asm volatile("" ::: "memory");
    }
#undef ALOAD
#undef BSTAGE
#undef AWRITE

    // transposed epilogue: stage 256(o) x 256(n) f32 in 2 LDS halves, store 1KB-contiguous rows
    float* ldsf = (float*)lds8;
    const int bidx = m0 >> 12;
    const int n_base = m0 & 4095;
    const int ccol = lane & 15;
    const int hi4 = (lane >> 4) * 4;
#pragma unroll
    for (int h = 0; h < 2; ++h) {
        if ((wn >> 1) == h) {
            const int o2b = (wn & 1) * 64;
#pragma unroll
            for (int mi = 0; mi < 8; ++mi)
#pragma unroll
                for (int ni = 0; ni < 4; ++ni) {
                    int o2 = o2b + ni * 16 + ccol;                 // 0..127
                    int nl = wm * 128 + mi * 16 + hi4;             // 0..255
                    *(f32x4*)&ldsf[o2 * 256 + (nl ^ ((o2 & 7) << 2))] = acc[mi][ni];
                }
        }
        asm volatile("s_waitcnt lgkmcnt(0)" ::: "memory");
        __builtin_amdgcn_s_barrier();
        asm volatile("" ::: "memory");
#pragma unroll 4
        for (int it = 0; it < 16; ++it) {
            int row = w * 16 + it;                                 // 0..127
            int o = n0 + h * 128 + row;                            // column in [0,2304)
            int sel = o / 768;
            int rem = o - sel * 768;
            f32x4 v = *(const f32x4*)&ldsf[row * 256 + ((lane * 4) ^ ((row & 7) << 2))];
            float* dst = dout + (size_t)(3 - sel) * SZQKV
                       + ((size_t)((rem >> 8) * 4 + bidx) * 256 + (rem & 255)) * 4096
                       + n_base + lane * 4;
            *(f32x4*)dst = v;
        }
        if (h == 0) {
            __builtin_amdgcn_s_barrier();
            asm volatile("" ::: "memory");
        }
    }
}

// ---------------- GEMM2: xo = attn @ w_proj^T + bias (transposed epilogue) ----------------
__global__ __launch_bounds__(512, 2) void gemm_proj(const unsigned short* __restrict__ A,
                                                    const unsigned short* __restrict__ Bw,
                                                    const float* __restrict__ bias,
                                                    float* __restrict__ dout) {
    __shared__ unsigned char lds8[131072];
    const int t = threadIdx.x;
    const int lane = t & 63;
    const int w = t >> 6;
    const int wm = w >> 2, wn = w & 3;

    const int cpx = gridDim.x >> 3;
    const int orig = blockIdx.x;
    const int wgid = (orig & 7) * cpx + (orig >> 3);
    const int bx = wgid / 3, by = wgid - bx * 3;
    const int m0 = bx * 256, n0 = by * 256;

    const unsigned char* Ab = (const unsigned char*)A;
    const unsigned char* Bb = (const unsigned char*)Bw;

    const int trow = t >> 3;
    const int jx = ((t & 7) ^ (trow & 7)) << 4;
    const size_t aBase = (size_t)(m0 + trow) * 1536 + jx;
    const size_t bBase = (size_t)(n0 + trow) * 1536 + jx;
    const int ldst = t * 16;

    const int rA = wm * 128 + (lane & 15);
    const int rB = wn * 64 + (lane & 15);
    const int xt0 = (((lane >> 4)) ^ (lane & 7)) << 4;
    const int xt1 = ((4 + (lane >> 4)) ^ (lane & 7)) << 4;

    f32x4 acc[8][4] = {};

#define STAGE(kt, bsel) do { \
    unsigned char* db_ = lds8 + (bsel) * 65536; \
    const size_t ko_ = (size_t)(kt) * 128; \
    GLDS16(Ab + aBase + ko_,          db_ + ldst); \
    GLDS16(Ab + aBase + ko_ + 98304,  db_ + ldst + 8192); \
    GLDS16(Ab + aBase + ko_ + 196608, db_ + ldst + 16384); \
    GLDS16(Ab + aBase + ko_ + 294912, db_ + ldst + 24576); \
    GLDS16(Bb + bBase + ko_,          db_ + 32768 + ldst); \
    GLDS16(Bb + bBase + ko_ + 98304,  db_ + 32768 + ldst + 8192); \
    GLDS16(Bb + bBase + ko_ + 196608, db_ + 32768 + ldst + 16384); \
    GLDS16(Bb + bBase + ko_ + 294912, db_ + 32768 + ldst + 24576); \
} while (0)

    STAGE(0, 0);
    for (int kt = 0; kt < 12; ++kt) {
        if (kt < 11) {
            STAGE(kt + 1, (kt + 1) & 1);
            asm volatile("s_waitcnt vmcnt(8)" ::: "memory");
        } else {
            asm volatile("s_waitcnt vmcnt(0)" ::: "memory");
        }
        __builtin_amdgcn_s_barrier();
        asm volatile("" ::: "memory");
        const unsigned char* bufA = lds8 + (kt & 1) * 65536;
        const unsigned char* bufB = bufA + 32768;
        bf16x8 av[4], bv[4];
        LDA4(0, xt0); LDB4(xt0); MM(0);
        LDA4(64, xt0); MM(4);
        LDA4(0, xt1); LDB4(xt1); MM(0);
        LDA4(64, xt1); MM(4);
        asm volatile("s_waitcnt lgkmcnt(0)" ::: "memory");
        __builtin_amdgcn_s_barrier();
        asm volatile("" ::: "memory");
    }
#undef STAGE

    // transposed epilogue: 2 halves over m; store 1KB-contiguous o-slices of out rows
    float* ldsf = (float*)lds8;
    const int ccol = lane & 15;
    const int hi4 = (lane >> 4) * 4;
#pragma unroll
    for (int h = 0; h < 2; ++h) {
        if (wm == h) {
#pragma unroll
            for (int mi = 0; mi < 8; ++mi)
#pragma unroll
                for (int ni = 0; ni < 4; ++ni) {
                    int o = wn * 64 + ni * 16 + ccol;              // 0..255
                    int m2b = mi * 16 + hi4;                       // 0..127
#pragma unroll
                    for (int r = 0; r < 4; ++r)
                        ldsf[(m2b + r) * 256 + (o ^ (((m2b + r) & 7) << 2))] = acc[mi][ni][r];
                }
        }
        asm volatile("s_waitcnt lgkmcnt(0)" ::: "memory");
        __builtin_amdgcn_s_barrier();
        asm volatile("" ::: "memory");
        f32x4 bv4 = *(const f32x4*)(bias + n0 + lane * 4);
#pragma unroll 4
        for (int it = 0; it < 16; ++it) {
            int m2 = w * 16 + it;                                  // 0..127
            f32x4 v = *(const f32x4*)&ldsf[m2 * 256 + ((lane * 4) ^ ((m2 & 7) << 2))];
            v = v + bv4;
            float* dst = dout + (size_t)(m0 + h * 128 + m2) * 768 + n0 + lane * 4;
            *(f32x4*)dst = v;
        }
        if (h == 0) {
            __builtin_amdgcn_s_barrier();
            asm volatile("" ::: "memory");
        }
    }
}

// ---------------- attention: read q/k/v f32 from d_out, write bf16 [b][n][c] ----------------
__global__ __launch_bounds__(256) void attn_kernel(const float* __restrict__ qkv,
                                                   unsigned short* __restrict__ attnbf) {
    const int chunk = blockIdx.x;  // 64 chunks of 64 n
    const int dil_i = blockIdx.y;  // 0..2
    const int b     = blockIdx.z;  // 0..3
    const int dil   = dil_i + 1;
    const int t  = threadIdx.x;
    const int h  = t >> 6;         // wave = head
    const int nl = t & 63;
    const int n  = chunk * 64 + nl;

    const size_t gb = (size_t)(dil_i * 4 + b) * 256 * 4096;
    const float* Q = qkv + (size_t)3 * SZQKV + gb;
    const float* K = qkv + (size_t)2 * SZQKV + gb;
    const float* V = qkv + (size_t)1 * SZQKV + gb;

    const int nm = n - dil, np = n + dil;
    const bool vm = (nm >= 0), vp = (np < 4096);
    const int nmc = vm ? nm : 0, npc = vp ? np : 4095;

    float s0 = 0.f, s1 = 0.f, s2 = 0.f;
    {
        const float* qrow = Q + (size_t)h * 64 * 4096;
        const float* krow = K + (size_t)h * 64 * 4096;
        for (int d = 0; d < 64; ++d) {
            float q = qrow[n];
            s0 += q * krow[nmc];
            s1 += q * krow[n];
            s2 += q * krow[npc];
            qrow += 4096; krow += 4096;
        }
    }
    s0 = vm ? s0 * 0.125f : 0.f;   // padded K-column -> exact 0 score (matches ref)
    s1 *= 0.125f;
    s2 = vp ? s2 * 0.125f : 0.f;
    float mx = fmaxf(0.f, fmaxf(s0, fmaxf(s1, s2)));
    float e0 = __expf(s0 - mx), e1 = __expf(s1 - mx), e2 = __expf(s2 - mx);
    // softmax over 9 slots: 6 structural zeros contribute 6*exp(-mx)
    float den = e0 + e1 + e2 + 6.f * __expf(-mx);
    float inv = 1.f / den;
    float p0 = vm ? e0 * inv : 0.f;
    float p1 = e1 * inv;
    float p2 = vp ? e2 * inv : 0.f;

    __shared__ unsigned short lout[256][65];  // [c'][n] bf16, padded row
    {
        const float* vrow = V + (size_t)h * 64 * 4096;
        for (int d = 0; d < 64; ++d) {
            float o = p0 * vrow[nmc] + p1 * vrow[n] + p2 * vrow[npc];
            lout[h * 64 + d][nl] = f2bf(o);
            vrow += 4096;
        }
    }
    __syncthreads();

    // write tile transposed: attnbf[(b*4096+n)*768 + dil_i*256 + c], c fastest
#pragma unroll
    for (int i = 0; i < 8; ++i) {
        int linear = i * 256 + t;   // 0..2047
        int nn   = linear >> 5;     // 0..63
        int cblk = linear & 31;     // 0..31 (8 channels each)
        union { unsigned short u[8]; f32x4 v; } tt;
#pragma unroll
        for (int j = 0; j < 8; ++j) tt.u[j] = lout[cblk * 8 + j][nn];
        unsigned short* dst = attnbf + (size_t)(b * 4096 + chunk * 64 + nn) * 768
                            + dil_i * 256 + cblk * 8;
        *(f32x4*)dst = tt.v;
    }
}

extern "C" void kernel_launch(void* const* d_in, const int* in_sizes, int n_in,
                              void* d_out, int out_size, void* d_ws, size_t ws_size,
                              hipStream_t stream) {
    const float* x     = (const float*)d_in[0];
    const float* wqkv  = (const float*)d_in[1];
    const float* wproj = (const float*)d_in[2];
    const float* bproj = (const float*)d_in[3];
    float* out = (float*)d_out;

    unsigned short* wqkvbf  = (unsigned short*)d_ws;          // 1769472
    unsigned short* wprojbf = wqkvbf + 1769472;               // 589824
    unsigned short* attnbf  = wprojbf + 589824;               // 12582912

    cast_w<<<1152, 256, 0, stream>>>(wqkv, wproj, wqkvbf);

    // qkv: M=16384 (64 m-tiles), Nw=2304 (9 n-tiles) -> 576 blocks (%8==0)
    gemm_qkv<<<dim3(576), 512, 0, stream>>>(x, wqkvbf, out);

    attn_kernel<<<dim3(64, 3, 4), 256, 0, stream>>>(out, attnbf);

    // proj: M=16384, Nw=768 (3 n-tiles) -> 192 blocks (%8==0)
    gemm_proj<<<dim3(192), 512, 0, stream>>>(attnbf, wprojbf, bproj, out);
}

// Round 6
// 176.674 us; speedup vs baseline: 1.1090x; 1.1090x over previous
//
#include <hip/hip_runtime.h>

typedef __attribute__((ext_vector_type(8))) short bf16x8;
typedef __attribute__((ext_vector_type(4))) float f32x4;

#define SZQKV 12582912  // B*N*C = one (q|k|v) output block, elements

__device__ __forceinline__ unsigned short f2bf(float f) {
    unsigned int u = __float_as_uint(f);
    unsigned int r = (u + 0x7FFFu + ((u >> 16) & 1u)) >> 16;
    return (unsigned short)r;
}

#define GLDS16(g, l) __builtin_amdgcn_global_load_lds( \
    (const __attribute__((address_space(1))) unsigned int*)(g), \
    (__attribute__((address_space(3))) unsigned int*)(l), 16, 0, 0)

// ---------------- cast f32 -> bf16 into workspace ----------------
__global__ void cast_all(const float* __restrict__ x,
                         const float* __restrict__ wqkv,
                         const float* __restrict__ wproj,
                         unsigned short* __restrict__ dst) {
    const int T1 = 12582912;       // x
    const int T2 = T1 + 1769472;   // + w_qkv
    const int T3 = T2 + 589824;    // + w_proj
    int stride = gridDim.x * blockDim.x * 4;
    for (int base = (blockIdx.x * blockDim.x + threadIdx.x) * 4; base < T3; base += stride) {
        const float* src; int off;
        if (base < T1)      { src = x;     off = base; }
        else if (base < T2) { src = wqkv;  off = base - T1; }
        else                { src = wproj; off = base - T2; }
        float4 v = *(const float4*)(src + off);
        ushort4 o;
        o.x = f2bf(v.x); o.y = f2bf(v.y); o.z = f2bf(v.z); o.w = f2bf(v.w);
        *(ushort4*)(dst + base) = o;
    }
}

// ---- 256x256 GEMM, BK=64, 8 waves (2m x 4n), fine 4-phase/K-tile pipeline ----
// A: [M][768] bf16. Bw: [Nw][768] bf16 (B^T). K = 768 = 12 K-tiles.
// LDS buf (64KB x2): regions A-ks0 @0, A-ks1 @16384, B-ks0 @32768, B-ks1 @49152;
// each 256 rows x 64B (32 cols bf16), phys chunk = logical ^ (row&3) (conflict-free b128).
// Phase g of tile t: {ds_read subtile ; stage half-region #(4t+g+5) ; 16 MFMA ; barrier}.
// Stage stream: (t,P0)->T+1.A-ks1, (t,P1)->T+1.B-ks0, (t,P2)->T+1.B-ks1, (t,P3)->T+2.A-ks0.
// Every overwrite target's last read finished >=1 barrier before the stage issue (derived).
// One vmcnt(2) per K-tile at P3 (all of T+1 landed; P3's own 2 loads stay in flight);
// barrier after it gives the all-waves guarantee. In-flight 2..10, drains only at tail.
template <int MODE>
__global__ __launch_bounds__(512, 2) void gemm8(const unsigned short* __restrict__ A,
                                                const unsigned short* __restrict__ Bw,
                                                const float* __restrict__ bias,
                                                float* __restrict__ dout,
                                                int nby) {
    __shared__ unsigned char lds8[131072];
    const int t = threadIdx.x;
    const int lane = t & 63;
    const int w = t >> 6;
    const int wm = w >> 2, wn = w & 3;   // 2m x 4n waves, 128x64 per wave

    // bijective XCD chunk swizzle (grid % 8 == 0)
    const int cpx = gridDim.x >> 3;
    const int orig = blockIdx.x;
    const int wgid = (orig & 7) * cpx + (orig >> 3);
    const int bx = wgid / nby, by = wgid - bx * nby;
    const int m0 = bx * 256, n0 = by * 256;

    const unsigned char* Ab = (const unsigned char*)A;
    const unsigned char* Bb = (const unsigned char*)Bw;

    // staging: slot s=q*512+t -> row r=s>>2 (0..255), phys chunk p=s&3;
    // logical chunk c = p ^ (r&3); (r+128)&3 == r&3 so c is shared by both loads.
    const int srow = t >> 2;
    const int sc = ((t & 3) ^ (srow & 3)) << 4;
    const size_t aSrc = (size_t)(m0 + srow) * 1536 + sc;   // + ks*64 + kt*128 (+196608 row+128)
    const size_t bSrc = (size_t)(n0 + srow) * 1536 + sc;
    const int ldst = t * 16;

    // fragment reads: row stride 64B; row&3 == lane&3 for all frags
    const int rA = wm * 128 + (lane & 15);
    const int rB = wn * 64 + (lane & 15);
    const int xt = (((lane >> 4)) ^ (lane & 3)) << 4;

    f32x4 acc[8][4] = {};

#define STG(reg_, srcb_, kt_, ks_) do { \
    const size_t so_ = (srcb_) + (size_t)(kt_) * 128 + (ks_) * 64; \
    GLDS16((ks_ ? Ab : Ab) + 0, (unsigned char*)0); \
} while (0)
#undef STG
// real stage macros (A-source and B-source variants)
#define STGA(regptr_, kt_, ks_) do { \
    const size_t so_ = aSrc + (size_t)(kt_) * 128 + (ks_) * 64; \
    GLDS16(Ab + so_,          (regptr_) + ldst); \
    GLDS16(Ab + so_ + 196608, (regptr_) + 8192 + ldst); \
} while (0)
#define STGB(regptr_, kt_, ks_) do { \
    const size_t so_ = bSrc + (size_t)(kt_) * 128 + (ks_) * 64; \
    GLDS16(Bb + so_,          (regptr_) + 8192 * 0 + ldst); \
    GLDS16(Bb + so_ + 196608, (regptr_) + 8192 + ldst); \
} while (0)

#define LDA4(cb_, ks_, mb_) do { \
    _Pragma("unroll") \
    for (int mi = 0; mi < 4; ++mi) \
        av[mi] = *(const bf16x8*)((cb_) + (ks_) * 16384 + (rA + (mb_) + mi * 16) * 64 + xt); \
} while (0)

#define LDB4(cb_, ks_) do { \
    _Pragma("unroll") \
    for (int ni = 0; ni < 4; ++ni) \
        bv[ni] = *(const bf16x8*)((cb_) + 32768 + (ks_) * 16384 + (rB + ni * 16) * 64 + xt); \
} while (0)

#define MM(rbase_) do { \
    __builtin_amdgcn_s_setprio(1); \
    _Pragma("unroll") \
    for (int mi = 0; mi < 4; ++mi) \
    _Pragma("unroll") \
    for (int ni = 0; ni < 4; ++ni) \
        acc[(rbase_) + mi][ni] = __builtin_amdgcn_mfma_f32_16x16x32_bf16(av[mi], bv[ni], acc[(rbase_) + mi][ni], 0, 0, 0); \
    __builtin_amdgcn_s_setprio(0); \
} while (0)

#define BAR() do { __builtin_amdgcn_s_barrier(); asm volatile("" ::: "memory"); } while (0)

    {   // prologue: half-regions #0..#4 (T0 complete + T1.A-ks0), 10 loads
        unsigned char* b0 = lds8;
        unsigned char* b1 = lds8 + 65536;
        STGA(b0,          0, 0);   // T0.A-ks0
        STGA(b0 + 16384,  0, 1);   // T0.A-ks1
        STGB(b0 + 32768,  0, 0);   // T0.B-ks0
        STGB(b0 + 49152,  0, 1);   // T0.B-ks1
        STGA(b1,          1, 0);   // T1.A-ks0
        asm volatile("s_waitcnt vmcnt(2)" ::: "memory");   // T0 landed
        BAR();
    }

    for (int kt = 0; kt < 12; ++kt) {
        unsigned char* cb = lds8 + (kt & 1) * 65536;
        unsigned char* nb = lds8 + ((kt + 1) & 1) * 65536;
        bf16x8 av[4], bv[4];
        // P0: ks0, mi0-3 ; stage T+1.A-ks1
        LDA4(cb, 0, 0); LDB4(cb, 0);
        if (kt < 11) STGA(nb + 16384, kt + 1, 1);
        MM(0);
        BAR();
        // P1: ks0, mi4-7 (bv reuse) ; stage T+1.B-ks0
        LDA4(cb, 0, 64);
        if (kt < 11) STGB(nb + 32768, kt + 1, 0);
        MM(4);
        BAR();
        // P2: ks1, mi0-3 ; stage T+1.B-ks1
        LDA4(cb, 1, 0); LDB4(cb, 1);
        if (kt < 11) STGB(nb + 49152, kt + 1, 1);
        MM(0);
        BAR();
        // P3: ks1, mi4-7 ; stage T+2.A-ks0 (same buf as cur; A-ks0 last read at P1)
        LDA4(cb, 1, 64);
        if (kt < 10) STGA(cb, kt + 2, 0);
        MM(4);
        if (kt < 10)      asm volatile("s_waitcnt vmcnt(2)" ::: "memory");  // T+1 landed
        else if (kt == 10) asm volatile("s_waitcnt vmcnt(0)" ::: "memory"); // tail drain
        BAR();
    }
#undef STGA
#undef STGB
#undef LDA4
#undef LDB4
#undef MM

    const int ccol = lane & 15;
    const int hi4 = (lane >> 4) * 4;
    float* ldsf = (float*)lds8;
    if (MODE == 0) {
        // transposed epilogue: stage 128(o) x 256(n) f32 halves, store 1KB-contiguous rows
        const int bidx = m0 >> 12;
        const int n_base = m0 & 4095;
#pragma unroll
        for (int h = 0; h < 2; ++h) {
            if ((wn >> 1) == h) {
                const int o2b = (wn & 1) * 64;
#pragma unroll
                for (int mi = 0; mi < 8; ++mi)
#pragma unroll
                    for (int ni = 0; ni < 4; ++ni) {
                        int o2 = o2b + ni * 16 + ccol;                 // 0..127
                        int nl = wm * 128 + mi * 16 + hi4;             // 0..255
                        *(f32x4*)&ldsf[o2 * 256 + (nl ^ ((o2 & 7) << 2))] = acc[mi][ni];
                    }
            }
            asm volatile("s_waitcnt lgkmcnt(0)" ::: "memory");
            __builtin_amdgcn_s_barrier();
            asm volatile("" ::: "memory");
#pragma unroll 4
            for (int it = 0; it < 16; ++it) {
                int row = w * 16 + it;                                 // 0..127
                int o = n0 + h * 128 + row;                            // column in [0,2304)
                int sel = o / 768;
                int rem = o - sel * 768;
                f32x4 v = *(const f32x4*)&ldsf[row * 256 + ((lane * 4) ^ ((row & 7) << 2))];
                float* dst = dout + (size_t)(3 - sel) * SZQKV
                           + ((size_t)((rem >> 8) * 4 + bidx) * 256 + (rem & 255)) * 4096
                           + n_base + lane * 4;
                *(f32x4*)dst = v;
            }
            if (h == 0) { __builtin_amdgcn_s_barrier(); asm volatile("" ::: "memory"); }
        }
    } else {
        // row-major epilogue with bias; 1KB-contiguous stores via LDS transpose staging
#pragma unroll
        for (int h = 0; h < 2; ++h) {
            if (wm == h) {
#pragma unroll
                for (int mi = 0; mi < 8; ++mi)
#pragma unroll
                    for (int ni = 0; ni < 4; ++ni) {
                        int o = wn * 64 + ni * 16 + ccol;              // 0..255
                        int m2b = mi * 16 + hi4;                       // 0..127
#pragma unroll
                        for (int r = 0; r < 4; ++r)
                            ldsf[(m2b + r) * 256 + (o ^ (((m2b + r) & 7) << 2))] = acc[mi][ni][r];
                    }
            }
            asm volatile("s_waitcnt lgkmcnt(0)" ::: "memory");
            __builtin_amdgcn_s_barrier();
            asm volatile("" ::: "memory");
            f32x4 bv4 = *(const f32x4*)(bias + n0 + lane * 4);
#pragma unroll 4
            for (int it = 0; it < 16; ++it) {
                int m2 = w * 16 + it;                                  // 0..127
                f32x4 v = *(const f32x4*)&ldsf[m2 * 256 + ((lane * 4) ^ ((m2 & 7) << 2))];
                v = v + bv4;
                float* dst = dout + (size_t)(m0 + h * 128 + m2) * 768 + n0 + lane * 4;
                *(f32x4*)dst = v;
            }
            if (h == 0) { __builtin_amdgcn_s_barrier(); asm volatile("" ::: "memory"); }
        }
    }
}

// ---------------- attention: read q/k/v f32 from d_out, write bf16 [b][n][c] ----------------
__global__ __launch_bounds__(256) void attn_kernel(const float* __restrict__ qkv,
                                                   unsigned short* __restrict__ attnbf) {
    const int chunk = blockIdx.x;  // 64 chunks of 64 n
    const int dil_i = blockIdx.y;  // 0..2
    const int b     = blockIdx.z;  // 0..3
    const int dil   = dil_i + 1;
    const int t  = threadIdx.x;
    const int h  = t >> 6;         // wave = head
    const int nl = t & 63;
    const int n  = chunk * 64 + nl;

    const size_t gb = (size_t)(dil_i * 4 + b) * 256 * 4096;
    const float* Q = qkv + (size_t)3 * SZQKV + gb;
    const float* K = qkv + (size_t)2 * SZQKV + gb;
    const float* V = qkv + (size_t)1 * SZQKV + gb;

    const int nm = n - dil, np = n + dil;
    const bool vm = (nm >= 0), vp = (np < 4096);
    const int nmc = vm ? nm : 0, npc = vp ? np : 4095;

    float s0 = 0.f, s1 = 0.f, s2 = 0.f;
    {
        const float* qrow = Q + (size_t)h * 64 * 4096;
        const float* krow = K + (size_t)h * 64 * 4096;
        for (int d = 0; d < 64; ++d) {
            float q = qrow[n];
            s0 += q * krow[nmc];
            s1 += q * krow[n];
            s2 += q * krow[npc];
            qrow += 4096; krow += 4096;
        }
    }
    s0 = vm ? s0 * 0.125f : 0.f;   // padded K-column -> exact 0 score (matches ref)
    s1 *= 0.125f;
    s2 = vp ? s2 * 0.125f : 0.f;
    float mx = fmaxf(0.f, fmaxf(s0, fmaxf(s1, s2)));
    float e0 = __expf(s0 - mx), e1 = __expf(s1 - mx), e2 = __expf(s2 - mx);
    // softmax over 9 slots: 6 structural zeros contribute 6*exp(-mx)
    float den = e0 + e1 + e2 + 6.f * __expf(-mx);
    float inv = 1.f / den;
    float p0 = vm ? e0 * inv : 0.f;
    float p1 = e1 * inv;
    float p2 = vp ? e2 * inv : 0.f;

    __shared__ unsigned short lout[256][65];  // [c'][n] bf16, padded row
    {
        const float* vrow = V + (size_t)h * 64 * 4096;
        for (int d = 0; d < 64; ++d) {
            float o = p0 * vrow[nmc] + p1 * vrow[n] + p2 * vrow[npc];
            lout[h * 64 + d][nl] = f2bf(o);
            vrow += 4096;
        }
    }
    __syncthreads();

    // write tile transposed: attnbf[(b*4096+n)*768 + dil_i*256 + c], c fastest
#pragma unroll
    for (int i = 0; i < 8; ++i) {
        int linear = i * 256 + t;   // 0..2047
        int nn   = linear >> 5;     // 0..63
        int cblk = linear & 31;     // 0..31 (8 channels each)
        union { unsigned short u[8]; f32x4 v; } tt;
#pragma unroll
        for (int j = 0; j < 8; ++j) tt.u[j] = lout[cblk * 8 + j][nn];
        unsigned short* dst = attnbf + (size_t)(b * 4096 + chunk * 64 + nn) * 768
                            + dil_i * 256 + cblk * 8;
        *(f32x4*)dst = tt.v;
    }
}

extern "C" void kernel_launch(void* const* d_in, const int* in_sizes, int n_in,
                              void* d_out, int out_size, void* d_ws, size_t ws_size,
                              hipStream_t stream) {
    const float* x     = (const float*)d_in[0];
    const float* wqkv  = (const float*)d_in[1];
    const float* wproj = (const float*)d_in[2];
    const float* bproj = (const float*)d_in[3];
    float* out = (float*)d_out;

    unsigned short* xbf     = (unsigned short*)d_ws;          // 12582912
    unsigned short* wqkvbf  = xbf + 12582912;                 // 1769472
    unsigned short* wprojbf = wqkvbf + 1769472;               // 589824
    unsigned short* attnbf  = wprojbf + 589824;               // 12582912

    cast_all<<<2048, 256, 0, stream>>>(x, wqkv, wproj, xbf);

    // qkv: M=16384 (64 m-tiles), Nw=2304 (9 n-tiles) -> 576 blocks (%8==0)
    gemm8<0><<<dim3(576), 512, 0, stream>>>(xbf, wqkvbf, nullptr, out, 9);

    attn_kernel<<<dim3(64, 3, 4), 256, 0, stream>>>(out, attnbf);

    // proj: M=16384, Nw=768 (3 n-tiles) -> 192 blocks (%8==0)
    gemm8<1><<<dim3(192), 512, 0, stream>>>(attnbf, wprojbf, bproj, out, 3);
}